// Round 1
// baseline (188.169 us; speedup 1.0000x reference)
//
#include <hip/hip_runtime.h>

// AttentionGroupPool: B=8192 rows, T=4096, 64 ragged groups (sizes cycle
// 32/64/96/64, cycle = 256 elems = 4 groups, 16 cycles).
// One block (256 thr) per row. Wave w at float4-iteration k covers exactly
// cycle c = w + 4k, so every group is a contiguous lane-segment of one wave.

#define TPB 256

__global__ __launch_bounds__(TPB) void agp_kernel(
    const float* __restrict__ H,
    const float* __restrict__ score_w,
    const float* __restrict__ score_b,
    float* __restrict__ Z,
    float* __restrict__ A,
    int T)  // = 4096
{
  const int b   = blockIdx.x;
  const int tid = threadIdx.x;
  const float4* row = (const float4*)(H + (size_t)b * T);

  // partial[k][tid] = sum of 4 consecutive floats at element 4*tid + 1024*k
  __shared__ float partial[4][TPB];

#pragma unroll
  for (int k = 0; k < 4; ++k) {
    float4 v = row[tid + TPB * k];           // coalesced 16B/lane
    partial[k][tid] = (v.x + v.y) + (v.z + v.w);
  }
  __syncthreads();

  if (tid < 64) {
    const int g = tid;                  // group id 0..63
    const int c = g >> 2;               // cycle 0..15
    const int j = g & 3;                // position in cycle
    const int k = c >> 2;               // which float4 iteration
    const int w = c & 3;                // which wave produced it

    // within-cycle starts/lengths in units of float4 (4 elems):
    const int   start4[4] = {0, 8, 24, 48};
    const int   len4[4]   = {8, 16, 24, 16};
    const float invsz[4]  = {1.f/32.f, 1.f/64.f, 1.f/96.f, 1.f/64.f};

    const float* p = &partial[k][64 * w + start4[j]];
    float s = 0.f;
    const int L = len4[j];
    for (int i = 0; i < L; ++i) s += p[i];

    const float G     = s * invsz[j];
    const float score = G * score_w[0] + score_b[0];

    // softmax over the 64 groups — all in wave 0, full-wave shuffles
    float m = score;
#pragma unroll
    for (int mask = 32; mask >= 1; mask >>= 1)
      m = fmaxf(m, __shfl_xor(m, mask));

    const float e  = __expf(score - m);
    float se = e;          // sum of exp
    float sg = e * G;      // sum of exp * G
#pragma unroll
    for (int mask = 32; mask >= 1; mask >>= 1) {
      se += __shfl_xor(se, mask);
      sg += __shfl_xor(sg, mask);
    }

    A[(size_t)b * 64 + g] = e / se;     // coalesced 64-float row write
    if (g == 0) Z[b] = sg / se;
  }
}

extern "C" void kernel_launch(void* const* d_in, const int* in_sizes, int n_in,
                              void* d_out, int out_size, void* d_ws, size_t ws_size,
                              hipStream_t stream) {
  const float* H  = (const float*)d_in[0];
  const float* sw = (const float*)d_in[1];
  const float* sb = (const float*)d_in[2];

  const int T = 4096;
  const int B = in_sizes[0] / T;        // 8192

  float* Z = (float*)d_out;             // [B]
  float* A = Z + B;                     // [B, 64] flattened after Z

  agp_kernel<<<B, TPB, 0, stream>>>(H, sw, sb, Z, A, T);
}